// Round 21
// baseline (319.737 us; speedup 1.0000x reference)
//
#include <hip/hip_runtime.h>

#define EPSB 1e-5f
#define NEG 0.2f

__device__ __forceinline__ float lrelu(float y) { return y >= 0.f ? y : NEG * y; }

// clang native vectors
typedef float floatx4 __attribute__((ext_vector_type(4)));
typedef short bf16x8 __attribute__((ext_vector_type(8)));
__device__ __forceinline__ void nt_store4(float4 v, float* addr) {
  floatx4 w = {v.x, v.y, v.z, v.w};
  __builtin_nontemporal_store(w, (floatx4*)addr);
}
__device__ __forceinline__ floatx4 nt_load4(const float* addr) {
  return __builtin_nontemporal_load((const floatx4*)addr);
}

// bf16 (RNE) pack/unpack for the u tensor
__device__ __forceinline__ unsigned short bfr(float f) {
  unsigned int b = __float_as_uint(f);
  return (unsigned short)((b + 0x7FFFu + ((b >> 16) & 1u)) >> 16);
}
__device__ __forceinline__ ushort4 f4bf(floatx4 a) {
  ushort4 r;
  r.x = bfr(a.x); r.y = bfr(a.y); r.z = bfr(a.z); r.w = bfr(a.w);
  return r;
}
__device__ __forceinline__ float4 bf4f(ushort4 h) {
  return make_float4(__uint_as_float((unsigned int)h.x << 16),
                     __uint_as_float((unsigned int)h.y << 16),
                     __uint_as_float((unsigned int)h.z << 16),
                     __uint_as_float((unsigned int)h.w << 16));
}

// barrier that does NOT drain vmcnt
__device__ __forceinline__ void barrier_nodrain() {
  asm volatile("s_waitcnt lgkmcnt(0)" ::: "memory");
  __builtin_amdgcn_s_barrier();
  __builtin_amdgcn_sched_barrier(0);
}

// ---------------------------------------------------------------------------
// Fused conv frontend (unchanged, validated): output xt[p][b][s].
// ---------------------------------------------------------------------------
__global__ __launch_bounds__(256) void k_front(
    const float* __restrict__ data, const float* __restrict__ w1,
    const float* __restrict__ w2, const float* __restrict__ w3,
    const float* __restrict__ lw, const float* __restrict__ bg,
    const float* __restrict__ bb, const float* __restrict__ bm,
    const float* __restrict__ bv, float* __restrict__ xt)
{
  __shared__ float x1s[32][132];
  __shared__ float x2s[32][40];
  __shared__ float x3s[32][20];
  const int b = blockIdx.x >> 3, q = blockIdx.x & 7, t = threadIdx.x;
  const int o1s = (937*q)/8, o1e = (937*(q+1))/8;
  const int o2s = (234*q)/8, o2e = (234*(q+1))/8;
  const int o3s = (116*q)/8, o3e = (116*(q+1))/8;
  int n2s = min(o2s, 2*o3s);
  int n2e = max(o2e, 2*(o3e-1)+4); if (n2e > 234) n2e = 234;
  int n1s = min(o1s, 4*n2s);
  int n1e = max(o1e, 4*(n2e-1)+5); if (n1e > 937) n1e = 937;
  const int w1w = n1e - n1s, w2w = n2e - n2s, w3w = o3e - o3s;

  for (int idx = t; idx < 32*w1w; idx += 256) {
    int c = idx / w1w, j = n1s + idx % w1w;
    float acc = 0.f;
    int base = 5*j - 2;
    #pragma unroll
    for (int k = 0; k < 5; ++k) {
      int pos = base + k;
      float d = (pos >= 0 && pos < 4681) ? data[b*4681 + pos] : 0.f;
      acc += w1[c*5 + k] * d;
    }
    float sc = bg[c] * rsqrtf(bv[c] + EPSB);
    x1s[c][j - n1s] = lrelu((acc - bm[c]) * sc + bb[c]);
  }
  __syncthreads();
  for (int idx = t; idx < 32*w2w; idx += 256) {
    int c = idx / w2w, j = n2s + idx % w2w;
    float acc = 0.f;
    int col = 4*j - n1s;
    for (int ci = 0; ci < 32; ++ci) {
      #pragma unroll
      for (int k = 0; k < 5; ++k) acc += w2[(c*32 + ci)*5 + k] * x1s[ci][col + k];
    }
    float sc = bg[32+c] * rsqrtf(bv[32+c] + EPSB);
    x2s[c][j - n2s] = lrelu((acc - bm[32+c]) * sc + bb[32+c]);
  }
  __syncthreads();
  for (int idx = t; idx < 32*w3w; idx += 256) {
    int c = idx / w3w, j = o3s + idx % w3w;
    float acc = 0.f;
    int col = 2*j - n2s;
    for (int ci = 0; ci < 32; ++ci) {
      #pragma unroll
      for (int k = 0; k < 4; ++k) acc += w3[(c*32 + ci)*4 + k] * x2s[ci][col + k];
    }
    float sc = bg[64+c] * rsqrtf(bv[64+c] + EPSB);
    x3s[c][j - o3s] = lrelu((acc - bm[64+c]) * sc + bb[64+c]);
  }
  __syncthreads();
  const int np1 = o1e - o1s, np2 = o2e - o2s, np3 = o3e - o3s;
  const int np = np1 + np2 + np3;
  for (int idx = t; idx < np*32; idx += 256) {
    int pi = idx >> 5, s = idx & 31;
    float acc = 0.f;
    int p;
    if (pi < np1) {
      int j = o1s + pi; p = j;
      int col = j - n1s;
      for (int ci = 0; ci < 32; ++ci) acc += lw[s*32 + ci] * x1s[ci][col];
    } else if (pi < np1 + np2) {
      int j = o2s + (pi - np1); p = 937 + j;
      int col = j - n2s;
      for (int ci = 0; ci < 32; ++ci) acc += lw[s*32 + ci] * x2s[ci][col];
    } else {
      int j = o3s + (pi - np1 - np2); p = 1171 + j;
      int col = j - o3s;
      for (int ci = 0; ci < 32; ++ci) acc += lw[s*32 + ci] * x3s[ci][col];
    }
    float sc = bg[96+s] * rsqrtf(bv[96+s] + EPSB);
    xt[p*1024 + b*32 + s] = lrelu((acc - bm[96+s]) * sc + bb[96+s]);
  }
}

// ---------------------------------------------------------------------------
// Pass A v9: W DIRECT-TO-REGISTER (no wbuf LDS, no DMA). Each W element is
// consumed by exactly one lane, and per nt-tile the wave's addresses cover a
// contiguous 2KB span -> per-lane float4 NT loads are fully coalesced.
// LDS = xs only (40KB) -> 4 blocks/CU (was 2). W regs double-buffered one p
// ahead; loop fully unrolled so all buffer indices are static.
// Math identical to R20's validated 3-term split -> absmax bit-identical.
// ---------------------------------------------------------------------------
__global__ __launch_bounds__(256) void k_uhat(
    const float* __restrict__ W, const float* __restrict__ xt,
    unsigned short* __restrict__ ubf, float* __restrict__ s0part)
{
  extern __shared__ float lds[];
  unsigned short* xs_hi = (unsigned short*)lds;        // [8p][32b][40]
  unsigned short* xs_lo = xs_hi + 10240;               // [8p][32b][40]
  const int t = threadIdx.x;
  const int wv = t >> 6, lane = t & 63;
  const int wi = blockIdx.x*4 + wv;
  const int l = wi % 40, chunk = wi / 40;
  const int p0 = chunk * 8;
  const float* Wl = W + (size_t)l * 1287 * 1280;
  const int row = lane & 15, g = lane >> 4;
  const int vq0 = row, vq1 = 16 + row;
  const int vq2 = (32 + row < 40) ? (32 + row) : 0;    // clamped (zeroed later)

  // stage x: fp32 -> (hi,lo) truncated bf16; zeros for p >= 1287
  for (int idx = t; idx < 2048; idx += 256) {
    int pl = idx >> 8, rem = idx & 255;
    int b = rem >> 3, s4 = rem & 7;
    int pg = p0 + pl;
    float4 v = make_float4(0.f, 0.f, 0.f, 0.f);
    if (pg < 1287) v = *(const float4*)(xt + pg*1024 + b*32 + s4*4);
    unsigned int b0 = __float_as_uint(v.x), b1 = __float_as_uint(v.y);
    unsigned int b2 = __float_as_uint(v.z), b3 = __float_as_uint(v.w);
    ushort4 h, lo;
    h.x = (unsigned short)(b0 >> 16); h.y = (unsigned short)(b1 >> 16);
    h.z = (unsigned short)(b2 >> 16); h.w = (unsigned short)(b3 >> 16);
    lo.x = (unsigned short)(__float_as_uint(v.x - __uint_as_float(b0 & 0xffff0000u)) >> 16);
    lo.y = (unsigned short)(__float_as_uint(v.y - __uint_as_float(b1 & 0xffff0000u)) >> 16);
    lo.z = (unsigned short)(__float_as_uint(v.z - __uint_as_float(b2 & 0xffff0000u)) >> 16);
    lo.w = (unsigned short)(__float_as_uint(v.w - __uint_as_float(b3 & 0xffff0000u)) >> 16);
    int off = pl*1280 + b*40 + s4*4;
    *(ushort4*)(xs_hi + off) = h;
    *(ushort4*)(xs_lo + off) = lo;
  }
  __syncthreads();

  floatx4 wr[2][6];
  // prologue: load W(p0) into buffer 0
  {
    const float* base = Wl + (size_t)p0*1280;
    wr[0][0] = nt_load4(base + vq0*32 + g*8);
    wr[0][1] = nt_load4(base + vq0*32 + g*8 + 4);
    wr[0][2] = nt_load4(base + vq1*32 + g*8);
    wr[0][3] = nt_load4(base + vq1*32 + g*8 + 4);
    wr[0][4] = nt_load4(base + vq2*32 + g*8);
    wr[0][5] = nt_load4(base + vq2*32 + g*8 + 4);
  }

  floatx4 s0acc[2][3];
  #pragma unroll
  for (int mt = 0; mt < 2; ++mt)
    #pragma unroll
    for (int nt = 0; nt < 3; ++nt)
      s0acc[mt][nt] = (floatx4){0.f, 0.f, 0.f, 0.f};

  #pragma unroll
  for (int pp = 0; pp < 8; ++pp) {
    const int p = p0 + pp;
    if (p >= 1287) break;
    const int cur = pp & 1, nxt = cur ^ 1;
    // prefetch W(p+1) into the other buffer (clamped source at the edge)
    {
      int pn = p + 1; if (pn > 1286) pn = 1286;
      const float* base = Wl + (size_t)pn*1280;
      wr[nxt][0] = nt_load4(base + vq0*32 + g*8);
      wr[nxt][1] = nt_load4(base + vq0*32 + g*8 + 4);
      wr[nxt][2] = nt_load4(base + vq1*32 + g*8);
      wr[nxt][3] = nt_load4(base + vq1*32 + g*8 + 4);
      wr[nxt][4] = nt_load4(base + vq2*32 + g*8);
      wr[nxt][5] = nt_load4(base + vq2*32 + g*8 + 4);
    }
    const unsigned short* xh = xs_hi + pp*1280;
    const unsigned short* xl = xs_lo + pp*1280;
    bf16x8 aH[2], aL[2];
    aH[0] = *(const bf16x8*)(xh + row*40 + g*8);
    aH[1] = *(const bf16x8*)(xh + (16 + row)*40 + g*8);
    aL[0] = *(const bf16x8*)(xl + row*40 + g*8);
    aL[1] = *(const bf16x8*)(xl + (16 + row)*40 + g*8);
    floatx4 acc[2][3];
    #pragma unroll
    for (int mt = 0; mt < 2; ++mt)
      #pragma unroll
      for (int nt = 0; nt < 3; ++nt)
        acc[mt][nt] = (floatx4){0.f, 0.f, 0.f, 0.f};
    #pragma unroll
    for (int nt = 0; nt < 3; ++nt) {
      const bool valid = (nt < 2) || (32 + row < 40);
      float ws[8];
      #pragma unroll
      for (int j = 0; j < 4; ++j) { ws[j] = wr[cur][nt*2][j]; ws[4+j] = wr[cur][nt*2+1][j]; }
      bf16x8 bH, bL;
      #pragma unroll
      for (int j = 0; j < 8; ++j) {
        unsigned int bits = __float_as_uint(ws[j]);
        unsigned short hs = (unsigned short)(bits >> 16);
        float lf = ws[j] - __uint_as_float(bits & 0xffff0000u);
        unsigned short lsv = (unsigned short)(__float_as_uint(lf) >> 16);
        bH[j] = valid ? (short)hs : (short)0;
        bL[j] = valid ? (short)lsv : (short)0;
      }
      #pragma unroll
      for (int mt = 0; mt < 2; ++mt) {
        acc[mt][nt] = __builtin_amdgcn_mfma_f32_16x16x32_bf16(aH[mt], bH, acc[mt][nt], 0, 0, 0);
        acc[mt][nt] = __builtin_amdgcn_mfma_f32_16x16x32_bf16(aH[mt], bL, acc[mt][nt], 0, 0, 0);
        acc[mt][nt] = __builtin_amdgcn_mfma_f32_16x16x32_bf16(aL[mt], bH, acc[mt][nt], 0, 0, 0);
      }
    }
    #pragma unroll
    for (int mt = 0; mt < 2; ++mt)
      #pragma unroll
      for (int nt = 0; nt < 3; ++nt) {
        int vq = nt*16 + row;
        if (vq < 40) {
          int q4 = mt*4 + g;
          *(ushort4*)(ubf + ((size_t)(q4*1287 + p))*6400 + l*160 + vq*4) = f4bf(acc[mt][nt]);
          s0acc[mt][nt] += acc[mt][nt];
        }
      }
  }
  #pragma unroll
  for (int mt = 0; mt < 2; ++mt)
    #pragma unroll
    for (int nt = 0; nt < 3; ++nt) {
      int vq = nt*16 + row;
      if (vq < 40) {
        int q4 = mt*4 + g;
        *(floatx4*)(s0part + (size_t)chunk*51200 + l*1280 + vq*32 + q4*4) = s0acc[mt][nt];
      }
    }
}

// ---------------------------------------------------------------------------
// squash kernels (unchanged, validated)
// ---------------------------------------------------------------------------
__global__ __launch_bounds__(64) void k_squash0(
    const float* __restrict__ s0, float* __restrict__ v0t)
{
  const int b = blockIdx.x / 40, l = blockIdx.x % 40, t = threadIdx.x;
  float s = 0.f;
  if (t < 40) s = s0[(l*40 + t)*32 + b] * (1.f/40.f);
  float sq = s*s;
  #pragma unroll
  for (int d = 1; d < 64; d <<= 1) sq += __shfl_xor(sq, d);
  float scale = sq > 0.f ? sq / ((1.f + sq) * sqrtf(sq)) : 0.f;
  if (t < 40) v0t[((size_t)(b >> 2)*1600 + l*40 + t)*4 + (b & 3)] = s * scale;
}

__global__ __launch_bounds__(64) void k_squash1(
    const float* __restrict__ sred, const float* __restrict__ v0t,
    float* __restrict__ v1t, float* __restrict__ vsum)
{
  const int b = blockIdx.x / 40, l = blockIdx.x % 40, t = threadIdx.x;
  float s = 0.f;
  size_t off = ((size_t)(b >> 2)*1600 + l*40 + t)*4 + (b & 3);
  if (t < 40) s = sred[off];
  float sq = s*s;
  #pragma unroll
  for (int d = 1; d < 64; d <<= 1) sq += __shfl_xor(sq, d);
  float scale = sq > 0.f ? sq / ((1.f + sq) * sqrtf(sq)) : 0.f;
  if (t < 40) {
    float v1 = s * scale;
    v1t[off] = v1;
    vsum[off] = v0t[off] + v1;
  }
}

__global__ __launch_bounds__(64) void k_final(
    const float* __restrict__ sred, float* __restrict__ out)
{
  const int b = blockIdx.x / 40, l = blockIdx.x % 40, t = threadIdx.x;
  float s = 0.f;
  if (t < 40) s = sred[((size_t)(b >> 2)*1600 + l*40 + t)*4 + (b & 3)];
  float sq = s*s, ss = s;
  #pragma unroll
  for (int d = 1; d < 64; d <<= 1) { sq += __shfl_xor(sq, d); ss += __shfl_xor(ss, d); }
  float scale = sq > 0.f ? sq / ((1.f + sq) * sqrtf(sq)) : 0.f;
  if (t == 0) out[b*40 + l] = ss * scale;
}

// ---------------------------------------------------------------------------
// k_route8 (unchanged from R20, validated): 2-phase pipelined fused routing,
// RPC=9 (143 chunks).
// ---------------------------------------------------------------------------
#define RPC 9
#define NCHUNK 143              // 143*9 = 1287 exactly
__global__ __launch_bounds__(400) void k_route8(
    const unsigned short* __restrict__ ubf, const float* __restrict__ vprev,
    float* __restrict__ spart, int rev)
{
  __shared__ float4 dred[2][400];
  __shared__ float dot_lds[160];      // [b4][40]
  __shared__ float c_lds[2][160];     // [b4][40]
  const int q4 = blockIdx.x & 7;
  const int chunk0 = blockIdx.x >> 3;
  const int chunk = rev ? (NCHUNK - 1 - chunk0) : chunk0;
  const int t = threadIdx.x;            // t = l*10 + vq
  const int l = t / 10;
  const int p0 = chunk * RPC;
  const ushort4* u4 = (const ushort4*)ubf;               // 8B units
  const float4* vp4 = (const float4*)vprev + (size_t)q4*1600;

  float4 vv[4], s4[4], fu[2][4];
  ushort4 uu[3][4];
  #pragma unroll
  for (int j = 0; j < 4; ++j) {
    vv[j] = vp4[t*4 + j];
    s4[j] = make_float4(0.f, 0.f, 0.f, 0.f);
  }
  {
    const ushort4* up0 = u4 + ((size_t)q4*1287 + p0)*1600;
    const ushort4* up1 = u4 + ((size_t)q4*1287 + p0 + 1)*1600;
    #pragma unroll
    for (int j = 0; j < 4; ++j) { uu[0][j] = up0[t*4 + j]; uu[1][j] = up1[t*4 + j]; }
    #pragma unroll
    for (int j = 0; j < 4; ++j) fu[0][j] = bf4f(uu[0][j]);
    float4 dp = make_float4(0.f, 0.f, 0.f, 0.f);
    #pragma unroll
    for (int j = 0; j < 4; ++j) {
      dp.x += fu[0][j].x*vv[j].x; dp.y += fu[0][j].y*vv[j].y;
      dp.z += fu[0][j].z*vv[j].z; dp.w += fu[0][j].w*vv[j].w;
    }
    dred[0][t] = dp;
  }
  barrier_nodrain();

  #pragma unroll
  for (int pl = 0; pl < RPC; ++pl) {
    const size_t qp = (size_t)q4*1287 + p0 + pl;
    // ---- Phase 1: B(pl) | D(pl-1) | issue raw loads for pl+2
    if (t < 160) {
      const int lr = t >> 2, b4 = t & 3;
      float d = 0.f;
      #pragma unroll
      for (int vq = 0; vq < 10; ++vq)
        d += ((const float*)&dred[pl & 1][lr*10 + vq])[b4];
      dot_lds[b4*40 + lr] = d;
    }
    if (pl >= 1) {
      const float* cl = c_lds[(pl - 1) & 1];
      float c0 = cl[l], c1 = cl[40 + l], c2 = cl[80 + l], c3 = cl[120 + l];
      #pragma unroll
      for (int j = 0; j < 4; ++j) {
        s4[j].x += fu[(pl - 1) & 1][j].x*c0; s4[j].y += fu[(pl - 1) & 1][j].y*c1;
        s4[j].z += fu[(pl - 1) & 1][j].z*c2; s4[j].w += fu[(pl - 1) & 1][j].w*c3;
      }
    }
    if (pl + 2 < RPC) {
      const ushort4* upn = u4 + (qp + 2)*1600;
      #pragma unroll
      for (int j = 0; j < 4; ++j) uu[(pl + 2) % 3][j] = upn[t*4 + j];
    }
    barrier_nodrain();
    // ---- Phase 2: C(pl) -> c_lds[pl&1] | A(pl+1) -> dred[(pl+1)&1]
    if (t < 256) {
      const int b4 = t >> 6, ll = t & 63;
      float d = (ll < 40) ? dot_lds[b4*40 + ll] : -1e30f;
      float m = d;
      #pragma unroll
      for (int off = 32; off; off >>= 1) m = fmaxf(m, __shfl_xor(m, off));
      float e = expf(d - m);
      float Z = e;
      #pragma unroll
      for (int off = 32; off; off >>= 1) Z += __shfl_xor(Z, off);
      if (ll < 40) c_lds[pl & 1][b4*40 + ll] = e * (1.f / Z);
    }
    if (pl + 1 < RPC) {
      #pragma unroll
      for (int j = 0; j < 4; ++j) fu[(pl + 1) & 1][j] = bf4f(uu[(pl + 1) % 3][j]);
      float4 dp = make_float4(0.f, 0.f, 0.f, 0.f);
      #pragma unroll
      for (int j = 0; j < 4; ++j) {
        dp.x += fu[(pl + 1) & 1][j].x*vv[j].x; dp.y += fu[(pl + 1) & 1][j].y*vv[j].y;
        dp.z += fu[(pl + 1) & 1][j].z*vv[j].z; dp.w += fu[(pl + 1) & 1][j].w*vv[j].w;
      }
      dred[(pl + 1) & 1][t] = dp;
    }
    barrier_nodrain();
  }
  // epilogue: D(RPC-1)
  {
    const float* cl = c_lds[(RPC - 1) & 1];
    float c0 = cl[l], c1 = cl[40 + l], c2 = cl[80 + l], c3 = cl[120 + l];
    #pragma unroll
    for (int j = 0; j < 4; ++j) {
      s4[j].x += fu[(RPC - 1) & 1][j].x*c0; s4[j].y += fu[(RPC - 1) & 1][j].y*c1;
      s4[j].z += fu[(RPC - 1) & 1][j].z*c2; s4[j].w += fu[(RPC - 1) & 1][j].w*c3;
    }
  }
  float* sp = spart + ((size_t)chunk*8 + q4)*6400;
  #pragma unroll
  for (int j = 0; j < 4; ++j)
    nt_store4(s4[j], sp + (t*4 + j)*4);
}

// sout[w] = sum_{c<n} src[c][w], w < 51200  (read-once source: NT loads)
__global__ __launch_bounds__(256) void k_reduceN(
    const float* __restrict__ src, float* __restrict__ sout, int n)
{
  const int w = blockIdx.x*256 + threadIdx.x;
  float s = 0.f;
  #pragma unroll 4
  for (int c = 0; c < n; ++c)
    s += __builtin_nontemporal_load(src + (size_t)c*51200 + w);
  sout[w] = s;
}

// ---------------------------------------------------------------------------
extern "C" void kernel_launch(void* const* d_in, const int* in_sizes, int n_in,
                              void* d_out, int out_size, void* d_ws, size_t ws_size,
                              hipStream_t stream)
{
  const float* data = (const float*)d_in[0];
  const float* w1   = (const float*)d_in[1];
  const float* w2   = (const float*)d_in[2];
  const float* w3   = (const float*)d_in[3];
  const float* lw   = (const float*)d_in[4];
  const float* bg   = (const float*)d_in[5];
  const float* bb   = (const float*)d_in[6];
  const float* bm   = (const float*)d_in[7];
  const float* bv   = (const float*)d_in[8];
  const float* W    = (const float*)d_in[9];
  float* out = (float*)d_out;

  unsigned short* ubf = (unsigned short*)d_ws;   // 65,894,400 ushorts (132MB)
  float* s0     = (float*)d_ws + 32947200;       // 51,200
  float* v0t    = s0 + 51200;                    // 51,200
  float* v1t    = v0t + 51200;                   // 51,200
  float* s1     = v1t + 51200;                   // 51,200
  float* vsum   = s1 + 51200;                    // 51,200
  float* xt     = vsum + 51200;                  // 1,317,888
  float* big    = xt + 1317888;
  float* s0part = big;                           // [161][51200] (dead after reduce)
  float* spart  = big;                           // [143][51200] (reuses region)
  // total ~165 MB

  const int KU_LDS = 2*10240*2;  // 40KB xs only
  hipFuncSetAttribute((const void*)k_uhat,
                      hipFuncAttributeMaxDynamicSharedMemorySize, KU_LDS);

  k_front<<<256, 256, 0, stream>>>(data, w1, w2, w3, lw, bg, bb, bm, bv, xt);
  k_uhat<<<1610, 256, KU_LDS, stream>>>(W, xt, ubf, s0part);
  k_reduceN<<<200, 256, 0, stream>>>(s0part, s0, 161);
  k_squash0<<<1280, 64, 0, stream>>>(s0, v0t);

  k_route8<<<NCHUNK*8, 400, 0, stream>>>(ubf, v0t, spart, 1);
  k_reduceN<<<200, 256, 0, stream>>>(spart, s1, NCHUNK);
  k_squash1<<<1280, 64, 0, stream>>>(s1, v0t, v1t, vsum);

  k_route8<<<NCHUNK*8, 400, 0, stream>>>(ubf, vsum, spart, 0);
  k_reduceN<<<200, 256, 0, stream>>>(spart, s0, NCHUNK);
  k_final<<<1280, 64, 0, stream>>>(s0, out);
}

// Round 22
// 311.959 us; speedup vs baseline: 1.0249x; 1.0249x over previous
//
#include <hip/hip_runtime.h>

#define EPSB 1e-5f
#define NEG 0.2f

__device__ __forceinline__ float lrelu(float y) { return y >= 0.f ? y : NEG * y; }

// async global->LDS 16B/lane (wave-uniform LDS dest, per-lane global src)
typedef const __attribute__((address_space(1))) unsigned int gas1_u32;
typedef __attribute__((address_space(3))) unsigned int as3_u32;
__device__ __forceinline__ void gload16nt(const float* g, float* l) {
  __builtin_amdgcn_global_load_lds((gas1_u32*)g, (as3_u32*)l, 16, 0, 2);
}
#define WAITVM(N) asm volatile("s_waitcnt vmcnt(" #N ")" ::: "memory")

// clang native vectors
typedef float floatx4 __attribute__((ext_vector_type(4)));
typedef short bf16x8 __attribute__((ext_vector_type(8)));
__device__ __forceinline__ void nt_store4(float4 v, float* addr) {
  floatx4 w = {v.x, v.y, v.z, v.w};
  __builtin_nontemporal_store(w, (floatx4*)addr);
}

// bf16 (RNE) pack/unpack for the u tensor
__device__ __forceinline__ unsigned short bfr(float f) {
  unsigned int b = __float_as_uint(f);
  return (unsigned short)((b + 0x7FFFu + ((b >> 16) & 1u)) >> 16);
}
__device__ __forceinline__ ushort4 f4bf(floatx4 a) {
  ushort4 r;
  r.x = bfr(a.x); r.y = bfr(a.y); r.z = bfr(a.z); r.w = bfr(a.w);
  return r;
}
__device__ __forceinline__ float4 bf4f(ushort4 h) {
  return make_float4(__uint_as_float((unsigned int)h.x << 16),
                     __uint_as_float((unsigned int)h.y << 16),
                     __uint_as_float((unsigned int)h.z << 16),
                     __uint_as_float((unsigned int)h.w << 16));
}

// barrier that does NOT drain vmcnt
__device__ __forceinline__ void barrier_nodrain() {
  asm volatile("s_waitcnt lgkmcnt(0)" ::: "memory");
  __builtin_amdgcn_s_barrier();
  __builtin_amdgcn_sched_barrier(0);
}

// ---------------------------------------------------------------------------
// Fused conv frontend (unchanged, validated): output xt[p][b][s].
// ---------------------------------------------------------------------------
__global__ __launch_bounds__(256) void k_front(
    const float* __restrict__ data, const float* __restrict__ w1,
    const float* __restrict__ w2, const float* __restrict__ w3,
    const float* __restrict__ lw, const float* __restrict__ bg,
    const float* __restrict__ bb, const float* __restrict__ bm,
    const float* __restrict__ bv, float* __restrict__ xt)
{
  __shared__ float x1s[32][132];
  __shared__ float x2s[32][40];
  __shared__ float x3s[32][20];
  const int b = blockIdx.x >> 3, q = blockIdx.x & 7, t = threadIdx.x;
  const int o1s = (937*q)/8, o1e = (937*(q+1))/8;
  const int o2s = (234*q)/8, o2e = (234*(q+1))/8;
  const int o3s = (116*q)/8, o3e = (116*(q+1))/8;
  int n2s = min(o2s, 2*o3s);
  int n2e = max(o2e, 2*(o3e-1)+4); if (n2e > 234) n2e = 234;
  int n1s = min(o1s, 4*n2s);
  int n1e = max(o1e, 4*(n2e-1)+5); if (n1e > 937) n1e = 937;
  const int w1w = n1e - n1s, w2w = n2e - n2s, w3w = o3e - o3s;

  for (int idx = t; idx < 32*w1w; idx += 256) {
    int c = idx / w1w, j = n1s + idx % w1w;
    float acc = 0.f;
    int base = 5*j - 2;
    #pragma unroll
    for (int k = 0; k < 5; ++k) {
      int pos = base + k;
      float d = (pos >= 0 && pos < 4681) ? data[b*4681 + pos] : 0.f;
      acc += w1[c*5 + k] * d;
    }
    float sc = bg[c] * rsqrtf(bv[c] + EPSB);
    x1s[c][j - n1s] = lrelu((acc - bm[c]) * sc + bb[c]);
  }
  __syncthreads();
  for (int idx = t; idx < 32*w2w; idx += 256) {
    int c = idx / w2w, j = n2s + idx % w2w;
    float acc = 0.f;
    int col = 4*j - n1s;
    for (int ci = 0; ci < 32; ++ci) {
      #pragma unroll
      for (int k = 0; k < 5; ++k) acc += w2[(c*32 + ci)*5 + k] * x1s[ci][col + k];
    }
    float sc = bg[32+c] * rsqrtf(bv[32+c] + EPSB);
    x2s[c][j - n2s] = lrelu((acc - bm[32+c]) * sc + bb[32+c]);
  }
  __syncthreads();
  for (int idx = t; idx < 32*w3w; idx += 256) {
    int c = idx / w3w, j = o3s + idx % w3w;
    float acc = 0.f;
    int col = 2*j - n2s;
    for (int ci = 0; ci < 32; ++ci) {
      #pragma unroll
      for (int k = 0; k < 4; ++k) acc += w3[(c*32 + ci)*4 + k] * x2s[ci][col + k];
    }
    float sc = bg[64+c] * rsqrtf(bv[64+c] + EPSB);
    x3s[c][j - o3s] = lrelu((acc - bm[64+c]) * sc + bb[64+c]);
  }
  __syncthreads();
  const int np1 = o1e - o1s, np2 = o2e - o2s, np3 = o3e - o3s;
  const int np = np1 + np2 + np3;
  for (int idx = t; idx < np*32; idx += 256) {
    int pi = idx >> 5, s = idx & 31;
    float acc = 0.f;
    int p;
    if (pi < np1) {
      int j = o1s + pi; p = j;
      int col = j - n1s;
      for (int ci = 0; ci < 32; ++ci) acc += lw[s*32 + ci] * x1s[ci][col];
    } else if (pi < np1 + np2) {
      int j = o2s + (pi - np1); p = 937 + j;
      int col = j - n2s;
      for (int ci = 0; ci < 32; ++ci) acc += lw[s*32 + ci] * x2s[ci][col];
    } else {
      int j = o3s + (pi - np1 - np2); p = 1171 + j;
      int col = j - o3s;
      for (int ci = 0; ci < 32; ++ci) acc += lw[s*32 + ci] * x3s[ci][col];
    }
    float sc = bg[96+s] * rsqrtf(bv[96+s] + EPSB);
    xt[p*1024 + b*32 + s] = lrelu((acc - bm[96+s]) * sc + bb[96+s]);
  }
}

// ---------------------------------------------------------------------------
// Pass A v7 (EXACT R20 bytes -- best measured 311.97us config; R21's
// W-direct-to-reg regressed): MFMA 3-term split, DMA W via LDS with counted
// vmcnt (11/17/12), bf16 u stores, fp32 s0part.
// ---------------------------------------------------------------------------
__global__ __launch_bounds__(256) void k_uhat(
    const float* __restrict__ W, const float* __restrict__ xt,
    unsigned short* __restrict__ ubf, float* __restrict__ s0part)
{
  extern __shared__ float lds[];
  float* wbuf = lds;                                       // [4][2][1280] f32
  unsigned short* xs_hi = (unsigned short*)(lds + 10240);  // [8p][32b][40]
  unsigned short* xs_lo = xs_hi + 10240;                   // [8p][32b][40]
  const int t = threadIdx.x;
  const int wv = t >> 6, lane = t & 63;
  const int wi = blockIdx.x*4 + wv;
  const int l = wi % 40, chunk = wi / 40;
  const int p0 = chunk * 8;
  float* myw = wbuf + wv * 2560;
  const float* Wl = W + (size_t)l * 1287 * 1280;
  const int row = lane & 15, g = lane >> 4;

  for (int idx = t; idx < 2048; idx += 256) {
    int pl = idx >> 8, rem = idx & 255;
    int b = rem >> 3, s4 = rem & 7;
    int pg = p0 + pl;
    float4 v = make_float4(0.f, 0.f, 0.f, 0.f);
    if (pg < 1287) v = *(const float4*)(xt + pg*1024 + b*32 + s4*4);
    unsigned int b0 = __float_as_uint(v.x), b1 = __float_as_uint(v.y);
    unsigned int b2 = __float_as_uint(v.z), b3 = __float_as_uint(v.w);
    ushort4 h, lo;
    h.x = (unsigned short)(b0 >> 16); h.y = (unsigned short)(b1 >> 16);
    h.z = (unsigned short)(b2 >> 16); h.w = (unsigned short)(b3 >> 16);
    lo.x = (unsigned short)(__float_as_uint(v.x - __uint_as_float(b0 & 0xffff0000u)) >> 16);
    lo.y = (unsigned short)(__float_as_uint(v.y - __uint_as_float(b1 & 0xffff0000u)) >> 16);
    lo.z = (unsigned short)(__float_as_uint(v.z - __uint_as_float(b2 & 0xffff0000u)) >> 16);
    lo.w = (unsigned short)(__float_as_uint(v.w - __uint_as_float(b3 & 0xffff0000u)) >> 16);
    int off = pl*1280 + b*40 + s4*4;
    *(ushort4*)(xs_hi + off) = h;
    *(ushort4*)(xs_lo + off) = lo;
  }
  #pragma unroll
  for (int i = 0; i < 5; ++i) {
    int gg = i*64 + lane, v = gg >> 3, s4 = (gg & 7) ^ (v & 7);
    gload16nt(Wl + (size_t)p0*1280 + (v*8 + s4)*4, myw + i*256);
  }
  #pragma unroll
  for (int i = 0; i < 5; ++i) {
    int gg = i*64 + lane, v = gg >> 3, s4 = (gg & 7) ^ (v & 7);
    gload16nt(Wl + (size_t)(p0+1)*1280 + (v*8 + s4)*4, myw + 1280 + i*256);
  }
  __syncthreads();

  floatx4 s0acc[2][3];
  #pragma unroll
  for (int mt = 0; mt < 2; ++mt)
    #pragma unroll
    for (int nt = 0; nt < 3; ++nt)
      s0acc[mt][nt] = (floatx4){0.f, 0.f, 0.f, 0.f};

  #pragma unroll
  for (int pp = 0; pp < 8; ++pp) {
    const int p = p0 + pp;
    if (p >= 1287) break;
    if (pp == 1)      WAITVM(11);
    else if (pp >= 2 && pp <= 6) WAITVM(17);
    else if (pp == 7) WAITVM(12);
    const float* wb = myw + (pp & 1)*1280;
    const unsigned short* xh = xs_hi + pp*1280;
    const unsigned short* xl = xs_lo + pp*1280;
    bf16x8 aH[2], aL[2];
    aH[0] = *(const bf16x8*)(xh + row*40 + g*8);
    aH[1] = *(const bf16x8*)(xh + (16 + row)*40 + g*8);
    aL[0] = *(const bf16x8*)(xl + row*40 + g*8);
    aL[1] = *(const bf16x8*)(xl + (16 + row)*40 + g*8);
    floatx4 acc[2][3];
    #pragma unroll
    for (int mt = 0; mt < 2; ++mt)
      #pragma unroll
      for (int nt = 0; nt < 3; ++nt)
        acc[mt][nt] = (floatx4){0.f, 0.f, 0.f, 0.f};
    #pragma unroll
    for (int nt = 0; nt < 3; ++nt) {
      int vq = nt*16 + row;
      bool valid = vq < 40;
      int vv = valid ? vq : 0;
      float4 w0 = *(const float4*)(wb + vv*32 + (((2*g) ^ (vv & 7)) << 2));
      float4 w1 = *(const float4*)(wb + vv*32 + (((2*g + 1) ^ (vv & 7)) << 2));
      float ws[8] = {w0.x, w0.y, w0.z, w0.w, w1.x, w1.y, w1.z, w1.w};
      bf16x8 bH, bL;
      #pragma unroll
      for (int j = 0; j < 8; ++j) {
        unsigned int bits = __float_as_uint(ws[j]);
        unsigned short hs = (unsigned short)(bits >> 16);
        float lf = ws[j] - __uint_as_float(bits & 0xffff0000u);
        unsigned short lsv = (unsigned short)(__float_as_uint(lf) >> 16);
        bH[j] = valid ? (short)hs : (short)0;
        bL[j] = valid ? (short)lsv : (short)0;
      }
      #pragma unroll
      for (int mt = 0; mt < 2; ++mt) {
        acc[mt][nt] = __builtin_amdgcn_mfma_f32_16x16x32_bf16(aH[mt], bH, acc[mt][nt], 0, 0, 0);
        acc[mt][nt] = __builtin_amdgcn_mfma_f32_16x16x32_bf16(aH[mt], bL, acc[mt][nt], 0, 0, 0);
        acc[mt][nt] = __builtin_amdgcn_mfma_f32_16x16x32_bf16(aL[mt], bH, acc[mt][nt], 0, 0, 0);
      }
    }
    if (pp < 6) {
      int psrc = p + 2; if (psrc > 1286) psrc = 1286;
      asm volatile("s_waitcnt lgkmcnt(0)" ::: "memory");
      __builtin_amdgcn_sched_barrier(0);
      #pragma unroll
      for (int i = 0; i < 5; ++i) {
        int gg = i*64 + lane, v = gg >> 3, s4 = (gg & 7) ^ (v & 7);
        gload16nt(Wl + (size_t)psrc*1280 + (v*8 + s4)*4, myw + (pp & 1)*1280 + i*256);
      }
    }
    #pragma unroll
    for (int mt = 0; mt < 2; ++mt)
      #pragma unroll
      for (int nt = 0; nt < 3; ++nt) {
        int vq = nt*16 + row;
        if (vq < 40) {
          int q4 = mt*4 + g;
          *(ushort4*)(ubf + ((size_t)(q4*1287 + p))*6400 + l*160 + vq*4) = f4bf(acc[mt][nt]);
          s0acc[mt][nt] += acc[mt][nt];
        }
      }
  }
  #pragma unroll
  for (int mt = 0; mt < 2; ++mt)
    #pragma unroll
    for (int nt = 0; nt < 3; ++nt) {
      int vq = nt*16 + row;
      if (vq < 40) {
        int q4 = mt*4 + g;
        *(floatx4*)(s0part + (size_t)chunk*51200 + l*1280 + vq*32 + q4*4) = s0acc[mt][nt];
      }
    }
}

// ---------------------------------------------------------------------------
// squash kernels (unchanged, validated)
// ---------------------------------------------------------------------------
__global__ __launch_bounds__(64) void k_squash0(
    const float* __restrict__ s0, float* __restrict__ v0t)
{
  const int b = blockIdx.x / 40, l = blockIdx.x % 40, t = threadIdx.x;
  float s = 0.f;
  if (t < 40) s = s0[(l*40 + t)*32 + b] * (1.f/40.f);
  float sq = s*s;
  #pragma unroll
  for (int d = 1; d < 64; d <<= 1) sq += __shfl_xor(sq, d);
  float scale = sq > 0.f ? sq / ((1.f + sq) * sqrtf(sq)) : 0.f;
  if (t < 40) v0t[((size_t)(b >> 2)*1600 + l*40 + t)*4 + (b & 3)] = s * scale;
}

__global__ __launch_bounds__(64) void k_squash1(
    const float* __restrict__ sred, const float* __restrict__ v0t,
    float* __restrict__ v1t, float* __restrict__ vsum)
{
  const int b = blockIdx.x / 40, l = blockIdx.x % 40, t = threadIdx.x;
  float s = 0.f;
  size_t off = ((size_t)(b >> 2)*1600 + l*40 + t)*4 + (b & 3);
  if (t < 40) s = sred[off];
  float sq = s*s;
  #pragma unroll
  for (int d = 1; d < 64; d <<= 1) sq += __shfl_xor(sq, d);
  float scale = sq > 0.f ? sq / ((1.f + sq) * sqrtf(sq)) : 0.f;
  if (t < 40) {
    float v1 = s * scale;
    v1t[off] = v1;
    vsum[off] = v0t[off] + v1;
  }
}

__global__ __launch_bounds__(64) void k_final(
    const float* __restrict__ sred, float* __restrict__ out)
{
  const int b = blockIdx.x / 40, l = blockIdx.x % 40, t = threadIdx.x;
  float s = 0.f;
  if (t < 40) s = sred[((size_t)(b >> 2)*1600 + l*40 + t)*4 + (b & 3)];
  float sq = s*s, ss = s;
  #pragma unroll
  for (int d = 1; d < 64; d <<= 1) { sq += __shfl_xor(sq, d); ss += __shfl_xor(ss, d); }
  float scale = sq > 0.f ? sq / ((1.f + sq) * sqrtf(sq)) : 0.f;
  if (t == 0) out[b*40 + l] = ss * scale;
}

// ---------------------------------------------------------------------------
// k_route8 (unchanged from R20, validated): 2-phase pipelined fused routing,
// RPC=9 (143 chunks).
// ---------------------------------------------------------------------------
#define RPC 9
#define NCHUNK 143              // 143*9 = 1287 exactly
__global__ __launch_bounds__(400) void k_route8(
    const unsigned short* __restrict__ ubf, const float* __restrict__ vprev,
    float* __restrict__ spart, int rev)
{
  __shared__ float4 dred[2][400];
  __shared__ float dot_lds[160];      // [b4][40]
  __shared__ float c_lds[2][160];     // [b4][40]
  const int q4 = blockIdx.x & 7;
  const int chunk0 = blockIdx.x >> 3;
  const int chunk = rev ? (NCHUNK - 1 - chunk0) : chunk0;
  const int t = threadIdx.x;            // t = l*10 + vq
  const int l = t / 10;
  const int p0 = chunk * RPC;
  const ushort4* u4 = (const ushort4*)ubf;               // 8B units
  const float4* vp4 = (const float4*)vprev + (size_t)q4*1600;

  float4 vv[4], s4[4], fu[2][4];
  ushort4 uu[3][4];
  #pragma unroll
  for (int j = 0; j < 4; ++j) {
    vv[j] = vp4[t*4 + j];
    s4[j] = make_float4(0.f, 0.f, 0.f, 0.f);
  }
  {
    const ushort4* up0 = u4 + ((size_t)q4*1287 + p0)*1600;
    const ushort4* up1 = u4 + ((size_t)q4*1287 + p0 + 1)*1600;
    #pragma unroll
    for (int j = 0; j < 4; ++j) { uu[0][j] = up0[t*4 + j]; uu[1][j] = up1[t*4 + j]; }
    #pragma unroll
    for (int j = 0; j < 4; ++j) fu[0][j] = bf4f(uu[0][j]);
    float4 dp = make_float4(0.f, 0.f, 0.f, 0.f);
    #pragma unroll
    for (int j = 0; j < 4; ++j) {
      dp.x += fu[0][j].x*vv[j].x; dp.y += fu[0][j].y*vv[j].y;
      dp.z += fu[0][j].z*vv[j].z; dp.w += fu[0][j].w*vv[j].w;
    }
    dred[0][t] = dp;
  }
  barrier_nodrain();

  #pragma unroll
  for (int pl = 0; pl < RPC; ++pl) {
    const size_t qp = (size_t)q4*1287 + p0 + pl;
    // ---- Phase 1: B(pl) | D(pl-1) | issue raw loads for pl+2
    if (t < 160) {
      const int lr = t >> 2, b4 = t & 3;
      float d = 0.f;
      #pragma unroll
      for (int vq = 0; vq < 10; ++vq)
        d += ((const float*)&dred[pl & 1][lr*10 + vq])[b4];
      dot_lds[b4*40 + lr] = d;
    }
    if (pl >= 1) {
      const float* cl = c_lds[(pl - 1) & 1];
      float c0 = cl[l], c1 = cl[40 + l], c2 = cl[80 + l], c3 = cl[120 + l];
      #pragma unroll
      for (int j = 0; j < 4; ++j) {
        s4[j].x += fu[(pl - 1) & 1][j].x*c0; s4[j].y += fu[(pl - 1) & 1][j].y*c1;
        s4[j].z += fu[(pl - 1) & 1][j].z*c2; s4[j].w += fu[(pl - 1) & 1][j].w*c3;
      }
    }
    if (pl + 2 < RPC) {
      const ushort4* upn = u4 + (qp + 2)*1600;
      #pragma unroll
      for (int j = 0; j < 4; ++j) uu[(pl + 2) % 3][j] = upn[t*4 + j];
    }
    barrier_nodrain();
    // ---- Phase 2: C(pl) -> c_lds[pl&1] | A(pl+1) -> dred[(pl+1)&1]
    if (t < 256) {
      const int b4 = t >> 6, ll = t & 63;
      float d = (ll < 40) ? dot_lds[b4*40 + ll] : -1e30f;
      float m = d;
      #pragma unroll
      for (int off = 32; off; off >>= 1) m = fmaxf(m, __shfl_xor(m, off));
      float e = expf(d - m);
      float Z = e;
      #pragma unroll
      for (int off = 32; off; off >>= 1) Z += __shfl_xor(Z, off);
      if (ll < 40) c_lds[pl & 1][b4*40 + ll] = e * (1.f / Z);
    }
    if (pl + 1 < RPC) {
      #pragma unroll
      for (int j = 0; j < 4; ++j) fu[(pl + 1) & 1][j] = bf4f(uu[(pl + 1) % 3][j]);
      float4 dp = make_float4(0.f, 0.f, 0.f, 0.f);
      #pragma unroll
      for (int j = 0; j < 4; ++j) {
        dp.x += fu[(pl + 1) & 1][j].x*vv[j].x; dp.y += fu[(pl + 1) & 1][j].y*vv[j].y;
        dp.z += fu[(pl + 1) & 1][j].z*vv[j].z; dp.w += fu[(pl + 1) & 1][j].w*vv[j].w;
      }
      dred[(pl + 1) & 1][t] = dp;
    }
    barrier_nodrain();
  }
  // epilogue: D(RPC-1)
  {
    const float* cl = c_lds[(RPC - 1) & 1];
    float c0 = cl[l], c1 = cl[40 + l], c2 = cl[80 + l], c3 = cl[120 + l];
    #pragma unroll
    for (int j = 0; j < 4; ++j) {
      s4[j].x += fu[(RPC - 1) & 1][j].x*c0; s4[j].y += fu[(RPC - 1) & 1][j].y*c1;
      s4[j].z += fu[(RPC - 1) & 1][j].z*c2; s4[j].w += fu[(RPC - 1) & 1][j].w*c3;
    }
  }
  float* sp = spart + ((size_t)chunk*8 + q4)*6400;
  #pragma unroll
  for (int j = 0; j < 4; ++j)
    nt_store4(s4[j], sp + (t*4 + j)*4);
}

// sout[w] = sum_{c<n} src[c][w], w < 51200  (read-once source: NT loads)
__global__ __launch_bounds__(256) void k_reduceN(
    const float* __restrict__ src, float* __restrict__ sout, int n)
{
  const int w = blockIdx.x*256 + threadIdx.x;
  float s = 0.f;
  #pragma unroll 4
  for (int c = 0; c < n; ++c)
    s += __builtin_nontemporal_load(src + (size_t)c*51200 + w);
  sout[w] = s;
}

// ---------------------------------------------------------------------------
extern "C" void kernel_launch(void* const* d_in, const int* in_sizes, int n_in,
                              void* d_out, int out_size, void* d_ws, size_t ws_size,
                              hipStream_t stream)
{
  const float* data = (const float*)d_in[0];
  const float* w1   = (const float*)d_in[1];
  const float* w2   = (const float*)d_in[2];
  const float* w3   = (const float*)d_in[3];
  const float* lw   = (const float*)d_in[4];
  const float* bg   = (const float*)d_in[5];
  const float* bb   = (const float*)d_in[6];
  const float* bm   = (const float*)d_in[7];
  const float* bv   = (const float*)d_in[8];
  const float* W    = (const float*)d_in[9];
  float* out = (float*)d_out;

  unsigned short* ubf = (unsigned short*)d_ws;   // 65,894,400 ushorts (132MB)
  float* s0     = (float*)d_ws + 32947200;       // 51,200
  float* v0t    = s0 + 51200;                    // 51,200
  float* v1t    = v0t + 51200;                   // 51,200
  float* s1     = v1t + 51200;                   // 51,200
  float* vsum   = s1 + 51200;                    // 51,200
  float* xt     = vsum + 51200;                  // 1,317,888
  float* big    = xt + 1317888;
  float* s0part = big;                           // [161][51200] (dead after reduce)
  float* spart  = big;                           // [143][51200] (reuses region)
  // total ~165 MB

  const int KU_LDS = 10240*4 + 2*10240*2;  // 40KB wbuf + 40KB xs = 81,920 B
  hipFuncSetAttribute((const void*)k_uhat,
                      hipFuncAttributeMaxDynamicSharedMemorySize, KU_LDS);

  k_front<<<256, 256, 0, stream>>>(data, w1, w2, w3, lw, bg, bb, bm, bv, xt);
  k_uhat<<<1610, 256, KU_LDS, stream>>>(W, xt, ubf, s0part);
  k_reduceN<<<200, 256, 0, stream>>>(s0part, s0, 161);
  k_squash0<<<1280, 64, 0, stream>>>(s0, v0t);

  k_route8<<<NCHUNK*8, 400, 0, stream>>>(ubf, v0t, spart, 1);
  k_reduceN<<<200, 256, 0, stream>>>(spart, s1, NCHUNK);
  k_squash1<<<1280, 64, 0, stream>>>(s1, v0t, v1t, vsum);

  k_route8<<<NCHUNK*8, 400, 0, stream>>>(ubf, vsum, spart, 0);
  k_reduceN<<<200, 256, 0, stream>>>(spart, s0, NCHUNK);
  k_final<<<1280, 64, 0, stream>>>(s0, out);
}